// Round 1
// baseline (2074.874 us; speedup 1.0000x reference)
//
#include <hip/hip_runtime.h>
#include <math.h>

#define B_ 4
#define S_ 2048
#define D_ 1024
#define H_ 16
#define HD_ 64
#define M_ (B_*S_)     // 8192

#define TILE 64
#define BK 32
#define PAD 4

// ---------------------------------------------------------------------------
// out(m,n) = sum_k A[m,k]*W[n,k] + bias[n], A:[M,D] row-major, W:[D,D] row-major
// output written in [B,H,S,HD] layout (head-split) for the attention stage.
// grid: 2048 = (M/64)*(D/64), block 256
// ---------------------------------------------------------------------------
__global__ __launch_bounds__(256) void gemm_proj(
    const float* __restrict__ A, const float* __restrict__ W,
    const float* __restrict__ bias, float* __restrict__ out)
{
    __shared__ float As[BK][TILE + PAD];
    __shared__ float Bs[BK][TILE + PAD];
    const int t  = threadIdx.x;
    const int m0 = (int)(blockIdx.x >> 4) * TILE;   // 128 row tiles
    const int n0 = (int)(blockIdx.x & 15) * TILE;   // 16 col tiles
    const int lr = t >> 3;            // 0..31
    const int lk = (t & 7) << 2;      // 0,4,...,28
    const int tr = t >> 4, tc = t & 15;
    const int r0 = tr << 2, c0 = tc << 2;

    float acc[4][4] = {};
    for (int k0 = 0; k0 < D_; k0 += BK) {
        float4 a0 = *(const float4*)&A[(size_t)(m0 + lr     ) * D_ + k0 + lk];
        float4 a1 = *(const float4*)&A[(size_t)(m0 + lr + 32) * D_ + k0 + lk];
        float4 w0 = *(const float4*)&W[(size_t)(n0 + lr     ) * D_ + k0 + lk];
        float4 w1 = *(const float4*)&W[(size_t)(n0 + lr + 32) * D_ + k0 + lk];
        __syncthreads();               // previous compute done before overwrite
        As[lk+0][lr]    = a0.x; As[lk+1][lr]    = a0.y; As[lk+2][lr]    = a0.z; As[lk+3][lr]    = a0.w;
        As[lk+0][lr+32] = a1.x; As[lk+1][lr+32] = a1.y; As[lk+2][lr+32] = a1.z; As[lk+3][lr+32] = a1.w;
        Bs[lk+0][lr]    = w0.x; Bs[lk+1][lr]    = w0.y; Bs[lk+2][lr]    = w0.z; Bs[lk+3][lr]    = w0.w;
        Bs[lk+0][lr+32] = w1.x; Bs[lk+1][lr+32] = w1.y; Bs[lk+2][lr+32] = w1.z; Bs[lk+3][lr+32] = w1.w;
        __syncthreads();
        #pragma unroll
        for (int kk = 0; kk < BK; ++kk) {
            float4 avv = *(const float4*)&As[kk][r0];
            float4 bvv = *(const float4*)&Bs[kk][c0];
            float av[4] = {avv.x, avv.y, avv.z, avv.w};
            float bv[4] = {bvv.x, bvv.y, bvv.z, bvv.w};
            #pragma unroll
            for (int i = 0; i < 4; ++i)
                #pragma unroll
                for (int j = 0; j < 4; ++j)
                    acc[i][j] = fmaf(av[i], bv[j], acc[i][j]);
        }
    }
    const int b = m0 / S_;
    const int h = n0 >> 6;           // n0 is a multiple of 64 -> whole tile in one head
    float4 bb = *(const float4*)&bias[n0 + c0];
    #pragma unroll
    for (int i = 0; i < 4; ++i) {
        const int s = (m0 % S_) + r0 + i;
        float4 o;
        o.x = acc[i][0] + bb.x; o.y = acc[i][1] + bb.y;
        o.z = acc[i][2] + bb.z; o.w = acc[i][3] + bb.w;
        *(float4*)&out[(((size_t)b * H_ + h) * S_ + s) * HD_ + c0] = o;
    }
}

// ---------------------------------------------------------------------------
// out[m*D + n] = sum_k Abhsd(m,k)*W[n,k] + bias[n]
// A is the attention output stored in [B,H,S,HD] layout.
// ---------------------------------------------------------------------------
__global__ __launch_bounds__(256) void gemm_out(
    const float* __restrict__ Abhsd, const float* __restrict__ W,
    const float* __restrict__ bias, float* __restrict__ out)
{
    __shared__ float As[BK][TILE + PAD];
    __shared__ float Bs[BK][TILE + PAD];
    const int t  = threadIdx.x;
    const int m0 = (int)(blockIdx.x >> 4) * TILE;
    const int n0 = (int)(blockIdx.x & 15) * TILE;
    const int lr = t >> 3;
    const int lk = (t & 7) << 2;
    const int tr = t >> 4, tc = t & 15;
    const int r0 = tr << 2, c0 = tc << 2;

    const int b = m0 / S_;
    const int sbase = m0 % S_;

    float acc[4][4] = {};
    for (int k0 = 0; k0 < D_; k0 += BK) {
        const int h0  = k0 >> 6;         // BK=32 divides 64: tile stays in one head
        const int off = k0 & 63;
        const float* Ab = &Abhsd[(((size_t)b * H_ + h0) * S_) * HD_];
        float4 a0 = *(const float4*)&Ab[(size_t)(sbase + lr     ) * HD_ + off + lk];
        float4 a1 = *(const float4*)&Ab[(size_t)(sbase + lr + 32) * HD_ + off + lk];
        float4 w0 = *(const float4*)&W[(size_t)(n0 + lr     ) * D_ + k0 + lk];
        float4 w1 = *(const float4*)&W[(size_t)(n0 + lr + 32) * D_ + k0 + lk];
        __syncthreads();
        As[lk+0][lr]    = a0.x; As[lk+1][lr]    = a0.y; As[lk+2][lr]    = a0.z; As[lk+3][lr]    = a0.w;
        As[lk+0][lr+32] = a1.x; As[lk+1][lr+32] = a1.y; As[lk+2][lr+32] = a1.z; As[lk+3][lr+32] = a1.w;
        Bs[lk+0][lr]    = w0.x; Bs[lk+1][lr]    = w0.y; Bs[lk+2][lr]    = w0.z; Bs[lk+3][lr]    = w0.w;
        Bs[lk+0][lr+32] = w1.x; Bs[lk+1][lr+32] = w1.y; Bs[lk+2][lr+32] = w1.z; Bs[lk+3][lr+32] = w1.w;
        __syncthreads();
        #pragma unroll
        for (int kk = 0; kk < BK; ++kk) {
            float4 avv = *(const float4*)&As[kk][r0];
            float4 bvv = *(const float4*)&Bs[kk][c0];
            float av[4] = {avv.x, avv.y, avv.z, avv.w};
            float bv[4] = {bvv.x, bvv.y, bvv.z, bvv.w};
            #pragma unroll
            for (int i = 0; i < 4; ++i)
                #pragma unroll
                for (int j = 0; j < 4; ++j)
                    acc[i][j] = fmaf(av[i], bv[j], acc[i][j]);
        }
    }
    float4 bb = *(const float4*)&bias[n0 + c0];
    #pragma unroll
    for (int i = 0; i < 4; ++i) {
        float4 o;
        o.x = acc[i][0] + bb.x; o.y = acc[i][1] + bb.y;
        o.z = acc[i][2] + bb.z; o.w = acc[i][3] + bb.w;
        *(float4*)&out[(size_t)(m0 + r0 + i) * D_ + n0 + c0] = o;
    }
}

// ---------------------------------------------------------------------------
// Flash attention, fp32. One block per (b,h, 64-row q tile).
// Q,K stored transposed [k][row] in LDS for float4 fragment reads.
// K-tile LDS is reused (unioned) as the P buffer to stay under 64KB.
// Output written in-place over the q buffer (each block owns its rows).
// ---------------------------------------------------------------------------
__global__ __launch_bounds__(256) void flash_attn(
    const float* __restrict__ qg, const float* __restrict__ kg,
    const float* __restrict__ vg, float* __restrict__ og)
{
    __shared__ float Qs[HD_][TILE + PAD];    // [k][row]
    __shared__ float KPs[TILE][TILE + PAD];  // K: [k][col]  /  P: [kv][row]
    __shared__ float Vs[TILE][HD_];          // [kv][hd]

    const int t   = threadIdx.x;
    const int nqt = S_ / TILE;               // 32
    const int qt  = blockIdx.x % nqt;
    const int bh  = blockIdx.x / nqt;
    const size_t base = (size_t)bh * S_ * HD_;
    const int s0  = qt * TILE;

    const int lr16 = t >> 4;                 // 0..15 (loader row group)
    const int lc4  = (t & 15) << 2;          // 0..60 (loader col*4)
    const int tr = t >> 4, tc = t & 15;
    const int r0 = tr << 2, c0 = tc << 2;

    // stage Q transposed
    #pragma unroll
    for (int i = 0; i < 4; ++i) {
        const int r = lr16 + i * 16;
        float4 qv = *(const float4*)&qg[base + (size_t)(s0 + r) * HD_ + lc4];
        Qs[lc4+0][r] = qv.x; Qs[lc4+1][r] = qv.y; Qs[lc4+2][r] = qv.z; Qs[lc4+3][r] = qv.w;
    }

    float m_run[4], l_run[4], O[4][4] = {};
    #pragma unroll
    for (int i = 0; i < 4; ++i) { m_run[i] = -1e30f; l_run[i] = 0.f; }

    for (int kt = 0; kt < S_ / TILE; ++kt) {
        const size_t kb = base + (size_t)(kt * TILE) * HD_;
        float4 kl[4], vl[4];
        #pragma unroll
        for (int i = 0; i < 4; ++i) {
            const int r = lr16 + i * 16;
            kl[i] = *(const float4*)&kg[kb + (size_t)r * HD_ + lc4];
            vl[i] = *(const float4*)&vg[kb + (size_t)r * HD_ + lc4];
        }
        __syncthreads();    // B1: previous PV reads of KPs(P)/Vs done (also covers Q stage)
        #pragma unroll
        for (int i = 0; i < 4; ++i) {
            const int r = lr16 + i * 16;
            KPs[lc4+0][r] = kl[i].x; KPs[lc4+1][r] = kl[i].y;
            KPs[lc4+2][r] = kl[i].z; KPs[lc4+3][r] = kl[i].w;
            *(float4*)&Vs[r][lc4] = vl[i];
        }
        __syncthreads();    // B2: tiles staged

        // S = (Q K^T) * 1/8
        float acc[4][4] = {};
        #pragma unroll
        for (int kk = 0; kk < HD_; ++kk) {
            float4 qvv = *(const float4*)&Qs[kk][r0];
            float4 kvv = *(const float4*)&KPs[kk][c0];
            float qv[4] = {qvv.x, qvv.y, qvv.z, qvv.w};
            float kv[4] = {kvv.x, kvv.y, kvv.z, kvv.w};
            #pragma unroll
            for (int i = 0; i < 4; ++i)
                #pragma unroll
                for (int j = 0; j < 4; ++j)
                    acc[i][j] = fmaf(qv[i], kv[j], acc[i][j]);
        }
        #pragma unroll
        for (int i = 0; i < 4; ++i)
            #pragma unroll
            for (int j = 0; j < 4; ++j)
                acc[i][j] *= 0.125f;

        // online softmax (rows shared across the 16 lanes with equal tr)
        float p[4][4], fac[4];
        #pragma unroll
        for (int i = 0; i < 4; ++i) {
            float mx = fmaxf(fmaxf(acc[i][0], acc[i][1]), fmaxf(acc[i][2], acc[i][3]));
            mx = fmaxf(mx, __shfl_xor(mx, 1, 16));
            mx = fmaxf(mx, __shfl_xor(mx, 2, 16));
            mx = fmaxf(mx, __shfl_xor(mx, 4, 16));
            mx = fmaxf(mx, __shfl_xor(mx, 8, 16));
            const float mnew = fmaxf(m_run[i], mx);
            fac[i] = __expf(m_run[i] - mnew);
            float sum = 0.f;
            #pragma unroll
            for (int j = 0; j < 4; ++j) { p[i][j] = __expf(acc[i][j] - mnew); sum += p[i][j]; }
            sum += __shfl_xor(sum, 1, 16);
            sum += __shfl_xor(sum, 2, 16);
            sum += __shfl_xor(sum, 4, 16);
            sum += __shfl_xor(sum, 8, 16);
            l_run[i] = l_run[i] * fac[i] + sum;
            m_run[i] = mnew;
            #pragma unroll
            for (int j = 0; j < 4; ++j) O[i][j] *= fac[i];
        }

        __syncthreads();    // B2.5: all K reads done before P overwrites KPs
        #pragma unroll
        for (int i = 0; i < 4; ++i)
            #pragma unroll
            for (int j = 0; j < 4; ++j)
                KPs[c0 + j][r0 + i] = p[i][j];   // P stored [kv][row]
        __syncthreads();    // B3: P staged

        // O += P V
        #pragma unroll
        for (int kv = 0; kv < TILE; ++kv) {
            float4 pvv = *(const float4*)&KPs[kv][r0];
            float4 vvv = *(const float4*)&Vs[kv][c0];
            float pv[4] = {pvv.x, pvv.y, pvv.z, pvv.w};
            float vv[4] = {vvv.x, vvv.y, vvv.z, vvv.w};
            #pragma unroll
            for (int i = 0; i < 4; ++i)
                #pragma unroll
                for (int j = 0; j < 4; ++j)
                    O[i][j] = fmaf(pv[i], vv[j], O[i][j]);
        }
    }

    // normalize + store (in-place over q: this block owns exactly these rows)
    #pragma unroll
    for (int i = 0; i < 4; ++i) {
        const float inv = 1.f / l_run[i];
        float4 o;
        o.x = O[i][0] * inv; o.y = O[i][1] * inv;
        o.z = O[i][2] * inv; o.w = O[i][3] * inv;
        *(float4*)&og[base + (size_t)(s0 + r0 + i) * HD_ + c0] = o;
    }
}

extern "C" void kernel_launch(void* const* d_in, const int* in_sizes, int n_in,
                              void* d_out, int out_size, void* d_ws, size_t ws_size,
                              hipStream_t stream) {
    const float* query = (const float*)d_in[0];
    const float* key_  = (const float*)d_in[1];
    const float* value = (const float*)d_in[2];
    const float* Wq    = (const float*)d_in[3];
    const float* bq    = (const float*)d_in[4];
    const float* Wk    = (const float*)d_in[5];
    const float* bk    = (const float*)d_in[6];
    const float* Wv    = (const float*)d_in[7];
    const float* bv    = (const float*)d_in[8];
    const float* Wo    = (const float*)d_in[9];
    const float* bo    = (const float*)d_in[10];
    float* out = (float*)d_out;

    float* qbuf = (float*)d_ws;                       // [B,H,S,HD]
    float* kbuf = qbuf + (size_t)M_ * D_;
    float* vbuf = kbuf + (size_t)M_ * D_;
    // total ws use: 3 * 8192*1024*4B = ~100.7 MB

    dim3 blk(256);
    dim3 gGemm(2048);   // (M/64)*(D/64)
    dim3 gAttn(B_ * H_ * (S_ / TILE));  // 2048

    gemm_proj<<<gGemm, blk, 0, stream>>>(query, Wq, bq, qbuf);
    gemm_proj<<<gGemm, blk, 0, stream>>>(key_,  Wk, bk, kbuf);
    gemm_proj<<<gGemm, blk, 0, stream>>>(value, Wv, bv, vbuf);
    flash_attn<<<gAttn, blk, 0, stream>>>(qbuf, kbuf, vbuf, qbuf);  // attn out in-place
    gemm_out<<<gGemm, blk, 0, stream>>>(qbuf, Wo, bo, out);
}

// Round 2
// 517.530 us; speedup vs baseline: 4.0092x; 4.0092x over previous
//
#include <hip/hip_runtime.h>
#include <math.h>

#define B_ 4
#define S_ 2048
#define D_ 1024
#define H_ 16
#define HD_ 64
#define M_ (B_*S_)     // 8192
#define BH_ (B_*H_)    // 64

typedef __attribute__((ext_vector_type(4))) float f32x4;
typedef __attribute__((ext_vector_type(8))) short bf16x8;
typedef unsigned short u16;

// ---------------- helpers ----------------
__device__ __forceinline__ u16 f2bf(float x) {
    unsigned u = __float_as_uint(x);
    u += 0x7fffu + ((u >> 16) & 1u);
    return (u16)(u >> 16);
}
__device__ __forceinline__ float bf2f(u16 h) {
    return __uint_as_float((unsigned)h << 16);
}
__device__ __forceinline__ void split1(float x, u16& hi, u16& lo) {
    hi = f2bf(x);
    lo = f2bf(x - bf2f(hi));
}
__device__ __forceinline__ void split4(float4 v, uint2& ph, uint2& pl) {
    u16 h0,h1,h2,h3,l0,l1,l2,l3;
    split1(v.x,h0,l0); split1(v.y,h1,l1); split1(v.z,h2,l2); split1(v.w,h3,l3);
    ph.x = (unsigned)h0 | ((unsigned)h1<<16); ph.y = (unsigned)h2 | ((unsigned)h3<<16);
    pl.x = (unsigned)l0 | ((unsigned)l1<<16); pl.y = (unsigned)l2 | ((unsigned)l3<<16);
}
__device__ __forceinline__ void gload_lds16(const void* g, void* l) {
    __builtin_amdgcn_global_load_lds(
        (const __attribute__((address_space(1))) void*)g,
        (__attribute__((address_space(3))) void*)l, 16, 0, 0);
}
#define MFMA(a,b,c) __builtin_amdgcn_mfma_f32_16x16x32_bf16((a),(b),(c),0,0,0)

// ---------------- W splitter: 4 segments of 1M floats ----------------
__global__ __launch_bounds__(256) void split_w_kernel(
    const float* __restrict__ w0, const float* __restrict__ w1,
    const float* __restrict__ w2, const float* __restrict__ w3,
    u16* __restrict__ hi, u16* __restrict__ lo)
{
    const float* src = (blockIdx.y==0)?w0:(blockIdx.y==1)?w1:(blockIdx.y==2)?w2:w3;
    size_t off = (size_t)blockIdx.y << 20;
    size_t i = ((size_t)blockIdx.x*256 + threadIdx.x)*4;
    float4 v = *(const float4*)&src[i];
    uint2 ph, pl; split4(v, ph, pl);
    *(uint2*)&hi[off + i] = ph;
    *(uint2*)&lo[off + i] = pl;
}

// ---------------------------------------------------------------------------
// Split-bf16 MFMA GEMM: C(m,n) = sum_k A[m,k]*W[n,k] + bias[n]
// MODE 0: out = qpack [bh][s][hi64|lo64], scaled 0.125
// MODE 1: out = khi/klo [bh][s][64]
// MODE 2: out = vthi/vtlo [bh][hd][s] (transposed)
// MODE 3: out = fp32 row-major [m][1024]; A gathered from [bh][s][64] f32
// PREB: B staged from pre-split Wh/Wl via global_load_lds; else reg-split Wf.
// ---------------------------------------------------------------------------
template<int MODE, bool PREB>
__global__ __launch_bounds__(256, 2) void gemm_mfma(
    const float* Af, const float* Wf,
    const u16* __restrict__ Wh, const u16* __restrict__ Wl,
    const float* __restrict__ bias,
    void* out0, void* out1)
{
    __shared__ u16 Ah[128][32];
    __shared__ u16 Al[128][32];
    __shared__ u16 Bh[128][32];
    __shared__ u16 Bl[128][32];

    const int t = threadIdx.x;
    const int lane = t & 63;
    const int w = t >> 6;
    const int wm = w >> 1, wn = w & 1;
    const int m0 = (int)(blockIdx.x >> 3) * 128;
    const int n0 = (int)(blockIdx.x & 7) * 128;

    const int arow = t >> 3;          // 0..31
    const int ac4  = (t & 7) * 4;     // 0..28

    f32x4 acc[4][4];
    #pragma unroll
    for (int i = 0; i < 4; ++i)
        #pragma unroll
        for (int j = 0; j < 4; ++j) { f32x4 z = {0.f,0.f,0.f,0.f}; acc[i][j] = z; }

    for (int k0 = 0; k0 < D_; k0 += 32) {
        float4 areg[4], breg[4];
        #pragma unroll
        for (int p = 0; p < 4; ++p) {
            int m = m0 + p*32 + arow;
            size_t addr;
            if constexpr (MODE == 3) {
                int b = m >> 11, s = m & 2047;
                int h = (k0 + ac4) >> 6, hd = (k0 + ac4) & 63;
                addr = ((((size_t)b*H_ + h)*S_) + s)*HD_ + hd;
            } else {
                addr = (size_t)m*D_ + k0 + ac4;
            }
            areg[p] = *(const float4*)&Af[addr];
        }
        if constexpr (!PREB) {
            #pragma unroll
            for (int p = 0; p < 4; ++p)
                breg[p] = *(const float4*)&Wf[(size_t)(n0 + p*32 + arow)*D_ + k0 + ac4];
        }
        __syncthreads();   // prior fragment reads complete
        #pragma unroll
        for (int p = 0; p < 4; ++p) {
            int row = p*32 + arow;
            int kw = ac4 ^ ((row & 3) << 3);
            uint2 ph, pl; split4(areg[p], ph, pl);
            *(uint2*)&Ah[row][kw] = ph;
            *(uint2*)&Al[row][kw] = pl;
        }
        if constexpr (!PREB) {
            #pragma unroll
            for (int p = 0; p < 4; ++p) {
                int row = p*32 + arow;
                int kw = ac4 ^ ((row & 3) << 3);
                uint2 ph, pl; split4(breg[p], ph, pl);
                *(uint2*)&Bh[row][kw] = ph;
                *(uint2*)&Bl[row][kw] = pl;
            }
        } else {
            #pragma unroll
            for (int c = 0; c < 2; ++c) {
                int lrow = w*32 + c*16;
                int row = lrow + (lane >> 2);
                int k8 = (lane & 3) * 8;
                int kw = k8 ^ ((row & 3) << 3);
                size_t src = (size_t)(n0 + row)*D_ + k0 + kw;
                gload_lds16(&Wh[src], &Bh[lrow][0]);
                gload_lds16(&Wl[src], &Bl[lrow][0]);
            }
        }
        __syncthreads();   // staged (vmcnt+lgkmcnt drained)

        bf16x8 ah[4], al[4], bh4[4], bl4[4];
        #pragma unroll
        for (int i = 0; i < 4; ++i) {
            int ml = wm*64 + i*16 + (lane & 15);
            int kwa = ((lane >> 4) * 8) ^ ((ml & 3) << 3);
            ah[i] = *(const bf16x8*)&Ah[ml][kwa];
            al[i] = *(const bf16x8*)&Al[ml][kwa];
            int nl = wn*64 + i*16 + (lane & 15);
            int kwb = ((lane >> 4) * 8) ^ ((nl & 3) << 3);
            bh4[i] = *(const bf16x8*)&Bh[nl][kwb];
            bl4[i] = *(const bf16x8*)&Bl[nl][kwb];
        }
        #pragma unroll
        for (int i = 0; i < 4; ++i)
            #pragma unroll
            for (int j = 0; j < 4; ++j) {
                f32x4 c = acc[i][j];
                c = MFMA(ah[i], bh4[j], c);
                c = MFMA(ah[i], bl4[j], c);
                c = MFMA(al[i], bh4[j], c);
                acc[i][j] = c;
            }
    }

    // epilogue
    #pragma unroll
    for (int i = 0; i < 4; ++i) {
        #pragma unroll
        for (int j = 0; j < 4; ++j) {
            int n = n0 + wn*64 + j*16 + (lane & 15);
            float bb = bias[n];
            int mbase = m0 + wm*64 + i*16 + (lane >> 4)*4;
            if constexpr (MODE == 3) {
                float* o = (float*)out0;
                #pragma unroll
                for (int r = 0; r < 4; ++r)
                    o[(size_t)(mbase + r)*D_ + n] = acc[i][j][r] + bb;
            } else if constexpr (MODE == 0) {
                u16* q = (u16*)out0;
                int b = mbase >> 11, h = n >> 6, hd = n & 63;
                size_t bh = (size_t)b*H_ + h;
                #pragma unroll
                for (int r = 0; r < 4; ++r) {
                    int s = (mbase + r) & 2047;
                    float v = (acc[i][j][r] + bb) * 0.125f;
                    u16 hi_, lo_; split1(v, hi_, lo_);
                    size_t base = (bh*S_ + s)*128;
                    q[base + hd] = hi_;
                    q[base + 64 + hd] = lo_;
                }
            } else if constexpr (MODE == 1) {
                u16* oh = (u16*)out0; u16* ol = (u16*)out1;
                int b = mbase >> 11, h = n >> 6, hd = n & 63;
                size_t bh = (size_t)b*H_ + h;
                #pragma unroll
                for (int r = 0; r < 4; ++r) {
                    int s = (mbase + r) & 2047;
                    float v = acc[i][j][r] + bb;
                    u16 hi_, lo_; split1(v, hi_, lo_);
                    size_t base = (bh*S_ + s)*64;
                    oh[base + hd] = hi_;
                    ol[base + hd] = lo_;
                }
            } else { // MODE 2: transposed V
                int b = mbase >> 11, h = n >> 6, hd = n & 63;
                int s0 = mbase & 2047;
                u16 h4[4], l4[4];
                #pragma unroll
                for (int r = 0; r < 4; ++r) {
                    float v = acc[i][j][r] + bb;
                    split1(v, h4[r], l4[r]);
                }
                uint2 ph, pl;
                ph.x = (unsigned)h4[0] | ((unsigned)h4[1]<<16);
                ph.y = (unsigned)h4[2] | ((unsigned)h4[3]<<16);
                pl.x = (unsigned)l4[0] | ((unsigned)l4[1]<<16);
                pl.y = (unsigned)l4[2] | ((unsigned)l4[3]<<16);
                size_t idx = (((size_t)b*H_ + h)*HD_ + hd)*S_ + s0;
                *(uint2*)&((u16*)out0)[idx] = ph;
                *(uint2*)&((u16*)out1)[idx] = pl;
            }
        }
    }
}

// ---------------------------------------------------------------------------
// MFMA flash attention. QBLK=128 (4 waves x 32 rows), KVBLK=64.
// Q frags direct from global qpack; K/V staged via global_load_lds with
// XOR-swizzled source; P through wave-private LDS; O fp32 in-place over qpack.
// ---------------------------------------------------------------------------
__global__ __launch_bounds__(256, 2) void attn_mfma(
    const u16* qpack,                                  // [bh][s][hi64|lo64]
    const u16* __restrict__ khi, const u16* __restrict__ klo,   // [bh][s][64]
    const u16* __restrict__ vthi, const u16* __restrict__ vtlo, // [bh][hd][s]
    float* Ofp)                                        // aliases qpack region
{
    __shared__ u16 Kh[64][64];
    __shared__ u16 Kl[64][64];
    __shared__ u16 Vth[64][64];  // [hd][kv]
    __shared__ u16 Vtl[64][64];
    __shared__ u16 Ps[128][64];

    const int t = threadIdx.x;
    const int lane = t & 63;
    const int w = t >> 6;
    const int qt = blockIdx.x & 15;
    const int bh = blockIdx.x >> 4;
    const size_t rowb = (size_t)bh * S_;
    const int q0 = qt * 128;

    // Q fragments (pre-scaled by 1/8 at projection)
    bf16x8 qh[2][2], ql[2][2];
    {
        int qr = q0 + w*32 + (lane & 15);
        #pragma unroll
        for (int mi = 0; mi < 2; ++mi)
            #pragma unroll
            for (int kk = 0; kk < 2; ++kk) {
                int d0 = kk*32 + (lane >> 4)*8;
                const u16* p = &qpack[(rowb + qr + mi*16)*128 + d0];
                qh[mi][kk] = *(const bf16x8*)p;
                ql[mi][kk] = *(const bf16x8*)(p + 64);
            }
    }

    f32x4 O[2][4];
    float m_run[2][4], l_run[2][4];
    #pragma unroll
    for (int mi = 0; mi < 2; ++mi) {
        #pragma unroll
        for (int oj = 0; oj < 4; ++oj) { f32x4 z = {0.f,0.f,0.f,0.f}; O[mi][oj] = z; }
        #pragma unroll
        for (int r = 0; r < 4; ++r) { m_run[mi][r] = -1e30f; l_run[mi][r] = 0.f; }
    }

    for (int kt = 0; kt < S_/64; ++kt) {
        __syncthreads();   // prior reads of K/V tiles complete
        #pragma unroll
        for (int c = 0; c < 2; ++c) {
            int lrow = w*16 + c*8;
            int row = lrow + (lane >> 3);
            int d8 = (lane & 7) * 8;
            int dsw = d8 ^ ((row & 7) << 3);
            size_t kg = (rowb + kt*64 + row)*64 + dsw;
            size_t vg = ((size_t)bh*HD_ + row)*S_ + kt*64 + dsw;
            gload_lds16(&khi[kg],  &Kh[lrow][0]);
            gload_lds16(&klo[kg],  &Kl[lrow][0]);
            gload_lds16(&vthi[vg], &Vth[lrow][0]);
            gload_lds16(&vtlo[vg], &Vtl[lrow][0]);
        }
        __syncthreads();   // staged

        // ---- QK^T (3-term split) ----
        f32x4 sa[2][4];
        #pragma unroll
        for (int mi = 0; mi < 2; ++mi)
            #pragma unroll
            for (int nj = 0; nj < 4; ++nj) { f32x4 z = {0.f,0.f,0.f,0.f}; sa[mi][nj] = z; }
        #pragma unroll
        for (int kk = 0; kk < 2; ++kk) {
            bf16x8 kbh[4], kbl[4];
            #pragma unroll
            for (int nj = 0; nj < 4; ++nj) {
                int kv = nj*16 + (lane & 15);
                int dw = (kk*32 + (lane >> 4)*8) ^ ((kv & 7) << 3);
                kbh[nj] = *(const bf16x8*)&Kh[kv][dw];
                kbl[nj] = *(const bf16x8*)&Kl[kv][dw];
            }
            #pragma unroll
            for (int mi = 0; mi < 2; ++mi)
                #pragma unroll
                for (int nj = 0; nj < 4; ++nj) {
                    f32x4 c = sa[mi][nj];
                    c = MFMA(qh[mi][kk], kbh[nj], c);
                    c = MFMA(qh[mi][kk], kbl[nj], c);
                    c = MFMA(ql[mi][kk], kbh[nj], c);
                    sa[mi][nj] = c;
                }
        }

        // ---- online softmax (rows shared across 16-lane groups) ----
        #pragma unroll
        for (int mi = 0; mi < 2; ++mi)
            #pragma unroll
            for (int r = 0; r < 4; ++r) {
                float mx = fmaxf(fmaxf(sa[mi][0][r], sa[mi][1][r]),
                                 fmaxf(sa[mi][2][r], sa[mi][3][r]));
                mx = fmaxf(mx, __shfl_xor(mx, 1, 16));
                mx = fmaxf(mx, __shfl_xor(mx, 2, 16));
                mx = fmaxf(mx, __shfl_xor(mx, 4, 16));
                mx = fmaxf(mx, __shfl_xor(mx, 8, 16));
                float mnew = fmaxf(m_run[mi][r], mx);
                float fac = __expf(m_run[mi][r] - mnew);
                float ssum = 0.f;
                #pragma unroll
                for (int nj = 0; nj < 4; ++nj) {
                    float pp = __expf(sa[mi][nj][r] - mnew);
                    sa[mi][nj][r] = pp;
                    ssum += pp;
                }
                ssum += __shfl_xor(ssum, 1, 16);
                ssum += __shfl_xor(ssum, 2, 16);
                ssum += __shfl_xor(ssum, 4, 16);
                ssum += __shfl_xor(ssum, 8, 16);
                l_run[mi][r] = l_run[mi][r]*fac + ssum;
                m_run[mi][r] = mnew;
                #pragma unroll
                for (int oj = 0; oj < 4; ++oj) O[mi][oj][r] *= fac;
            }

        // ---- P -> LDS (wave-private rows, swizzled) ----
        #pragma unroll
        for (int mi = 0; mi < 2; ++mi)
            #pragma unroll
            for (int nj = 0; nj < 4; ++nj)
                #pragma unroll
                for (int r = 0; r < 4; ++r) {
                    int q = w*32 + mi*16 + (lane >> 4)*4 + r;
                    int kv = nj*16 + (lane & 15);
                    Ps[q][kv ^ ((q & 7) << 3)] = f2bf(sa[mi][nj][r]);
                }

        // ---- PV (V 2-term) ----
        #pragma unroll
        for (int k2 = 0; k2 < 2; ++k2) {
            bf16x8 pa[2], vbh[4], vbl[4];
            #pragma unroll
            for (int mi = 0; mi < 2; ++mi) {
                int q = w*32 + mi*16 + (lane & 15);
                int kw = (k2*32 + (lane >> 4)*8) ^ ((q & 7) << 3);
                pa[mi] = *(const bf16x8*)&Ps[q][kw];
            }
            #pragma unroll
            for (int oj = 0; oj < 4; ++oj) {
                int hd = oj*16 + (lane & 15);
                int kw = (k2*32 + (lane >> 4)*8) ^ ((hd & 7) << 3);
                vbh[oj] = *(const bf16x8*)&Vth[hd][kw];
                vbl[oj] = *(const bf16x8*)&Vtl[hd][kw];
            }
            #pragma unroll
            for (int mi = 0; mi < 2; ++mi)
                #pragma unroll
                for (int oj = 0; oj < 4; ++oj) {
                    f32x4 c = O[mi][oj];
                    c = MFMA(pa[mi], vbh[oj], c);
                    c = MFMA(pa[mi], vbl[oj], c);
                    O[mi][oj] = c;
                }
        }
    }

    // ---- normalize + store fp32 (in-place over own qpack rows) ----
    #pragma unroll
    for (int mi = 0; mi < 2; ++mi)
        #pragma unroll
        for (int r = 0; r < 4; ++r) {
            float inv = 1.f / l_run[mi][r];
            int q = q0 + w*32 + mi*16 + (lane >> 4)*4 + r;
            #pragma unroll
            for (int oj = 0; oj < 4; ++oj) {
                int hd = oj*16 + (lane & 15);
                Ofp[(rowb + q)*HD_ + hd] = O[mi][oj][r] * inv;
            }
        }
}

extern "C" void kernel_launch(void* const* d_in, const int* in_sizes, int n_in,
                              void* d_out, int out_size, void* d_ws, size_t ws_size,
                              hipStream_t stream) {
    const float* query = (const float*)d_in[0];
    const float* key_  = (const float*)d_in[1];
    const float* value = (const float*)d_in[2];
    const float* Wq    = (const float*)d_in[3];
    const float* bq    = (const float*)d_in[4];
    const float* Wk    = (const float*)d_in[5];
    const float* bk    = (const float*)d_in[6];
    const float* Wv    = (const float*)d_in[7];
    const float* bv    = (const float*)d_in[8];
    const float* Wo    = (const float*)d_in[9];
    const float* bo    = (const float*)d_in[10];
    float* out = (float*)d_out;

    char* wsb = (char*)d_ws;
    const size_t SZ_QPACK = (size_t)BH_*S_*256;       // 33.55 MB
    const size_t SZ_ARR   = (size_t)BH_*S_*64*2;      // 16.78 MB (bf16 [bh][s][64])
    u16* qpack = (u16*)wsb;
    u16* khi   = (u16*)(wsb + SZ_QPACK);
    u16* klo   = (u16*)(wsb + SZ_QPACK + SZ_ARR);
    u16* vthi  = (u16*)(wsb + SZ_QPACK + 2*SZ_ARR);
    u16* vtlo  = (u16*)(wsb + SZ_QPACK + 3*SZ_ARR);
    u16* Whi   = (u16*)(wsb + SZ_QPACK + 4*SZ_ARR);   // [4][1<<20]
    u16* Wlo   = Whi + ((size_t)4 << 20);
    const size_t NEED_FULL = SZ_QPACK + 4*SZ_ARR + ((size_t)16 << 20);
    const bool preb = ws_size >= NEED_FULL;

    dim3 blk(256);
    dim3 gGemm(512);    // (8192/128)*(1024/128)
    dim3 gAttn(BH_ * (S_/128));  // 1024

    if (preb) {
        split_w_kernel<<<dim3(1024,4), blk, 0, stream>>>(Wq, Wk, Wv, Wo, Whi, Wlo);
        gemm_mfma<0,true><<<gGemm, blk, 0, stream>>>(query, nullptr, Whi + ((size_t)0<<20), Wlo + ((size_t)0<<20), bq, qpack, nullptr);
        gemm_mfma<1,true><<<gGemm, blk, 0, stream>>>(key_,  nullptr, Whi + ((size_t)1<<20), Wlo + ((size_t)1<<20), bk, khi, klo);
        gemm_mfma<2,true><<<gGemm, blk, 0, stream>>>(value, nullptr, Whi + ((size_t)2<<20), Wlo + ((size_t)2<<20), bv, vthi, vtlo);
    } else {
        gemm_mfma<0,false><<<gGemm, blk, 0, stream>>>(query, Wq, nullptr, nullptr, bq, qpack, nullptr);
        gemm_mfma<1,false><<<gGemm, blk, 0, stream>>>(key_,  Wk, nullptr, nullptr, bk, khi, klo);
        gemm_mfma<2,false><<<gGemm, blk, 0, stream>>>(value, Wv, nullptr, nullptr, bv, vthi, vtlo);
    }
    attn_mfma<<<gAttn, blk, 0, stream>>>(qpack, khi, klo, vthi, vtlo, (float*)qpack);
    if (preb) {
        gemm_mfma<3,true><<<gGemm, blk, 0, stream>>>((const float*)qpack, nullptr, Whi + ((size_t)3<<20), Wlo + ((size_t)3<<20), bo, out, nullptr);
    } else {
        gemm_mfma<3,false><<<gGemm, blk, 0, stream>>>((const float*)qpack, Wo, nullptr, nullptr, bo, out, nullptr);
    }
}